// Round 9
// baseline (476.864 us; speedup 1.0000x reference)
//
#include <hip/hip_runtime.h>
#include <hip/hip_bf16.h>
#include <hip/hip_fp16.h>
#include <stdint.h>

// ---------------------------------------------------------------------------
// GCN forward on MI355X.
//   CSR build via 196-bucket counting sort (bucket = col>>9, 512 nodes each).
//     k_transform1 : t1raw = x @ W1 (wave-per-row, W1 in regs, fp16 out,
//                    unscaled; dis applied in k_pass2). Block 0 also zeroes
//                    the 196 global bucket cursors.
//     k_scatter1   : single-pass LDS-multisplit scatter (count in LDS, scan,
//                    atomic-reserve per-bucket region, stage 60KB LDS
//                    bucket-ordered, coalesced flush). Rounds 3-6 lesson:
//                    scattered 4B stores over 25.6MB hit an L2 RMW wall.
//     k_bscan      : exclusive scan of bucket counts -> bbase
//     k_pass2      : per-bucket hist -> rowptr/dis, t1 *= dis, csr fill.
//   Layers (agg commutes with dense: A(XW)=(AX)W; 16->32->16 chain and the
//   classifier fused into agg epilogues; h2 never materialized):
//     t1  = (x @ W1) * dis                        (k_transform1 + k_pass2)
//     hs1 = relu(dis*gather(t1) + b1) * dis       (k_agg_rb)
//     t3  = (relu((dis*gather(hs1))@W2+b2)@W3)*dis (k_agg_mid)
//     h   = relu(dis*gather(t3) + b3) -> outh
//     out = h @ Wc + bc               -> outc      (k_agg_out)
//   AGG = WAVE-PER-NODE (round-8 lesson): with 4 nodes/wave (group-per-node)
//   every hs VMEM instruction touched 4 scattered 32B segments and 16 edges
//   cost 16 such instrs (~64 TA cyc) -> aggs were TA-divergence-bound
//   (~42us/layer model, ~50 observed). Wave-per-node: lane L = (edge-slot
//   L>>4, feature L&15); one VMEM loads 4 edges of the SAME node -> 16 edges
//   = 4 hs instrs + 1 coalesced csr load (~18 TA cyc). Indices distributed
//   by ds_bpermute (DS pipe, parallel to TA). Degree loop is per-wave: no
//   cross-node lockstep waste. Reduce = shfl_xor(16)+shfl_xor(32) once.
//   Gathered arrays (t1, hs1, t3) stored FP16 (3.2MB -> fits 4MB per-XCD
//   L2); fp32 accumulate. No fp atomics anywhere. 7 launches total.
// ---------------------------------------------------------------------------

#define MS_CHUNK 15360  // 60*256 edges per multisplit block (60KB staging)

__device__ __forceinline__ int blockScanExclusive256(int v, int* wsum) {
  int lane = threadIdx.x & 63;
  int wid  = threadIdx.x >> 6;
  int inc = v;
#pragma unroll
  for (int d = 1; d < 64; d <<= 1) {
    int y = __shfl_up(inc, d, 64);
    if (lane >= d) inc += y;
  }
  if (lane == 63) wsum[wid] = inc;
  __syncthreads();
  if (threadIdx.x == 0) {
    int s = 0;
#pragma unroll
    for (int w = 0; w < 4; ++w) { int t = wsum[w]; wsum[w] = s; s += t; }
  }
  __syncthreads();
  return inc - v + wsum[wid];
}

__device__ __forceinline__ int blockScanExclusive512(int v, int* wsum) {
  int lane = threadIdx.x & 63;
  int wid  = threadIdx.x >> 6;  // 0..7
  int inc = v;
#pragma unroll
  for (int d = 1; d < 64; d <<= 1) {
    int y = __shfl_up(inc, d, 64);
    if (lane >= d) inc += y;
  }
  if (lane == 63) wsum[wid] = inc;
  __syncthreads();
  if (threadIdx.x == 0) {
    int s = 0;
#pragma unroll
    for (int w = 0; w < 8; ++w) { int t = wsum[w]; wsum[w] = s; s += t; }
  }
  __syncthreads();
  return inc - v + wsum[wid];
}

// ---- bucket exclusive scan (1 block): counts (cursor) -> bbase ----
__global__ __launch_bounds__(256) void k_bscan(const int* __restrict__ counts,
                                               int* __restrict__ bbase,
                                               int nb, int etot) {
  __shared__ int wsum[4];
  __shared__ int carry_s;
  if (threadIdx.x == 0) carry_s = 0;
  __syncthreads();
  for (int base = 0; base < nb; base += 256) {
    int i = base + threadIdx.x;
    int v = (i < nb) ? counts[i] : 0;
    int ex = blockScanExclusive256(v, wsum);
    int c = carry_s;
    __syncthreads();
    if (i < nb) bbase[i] = ex + c;
    if (threadIdx.x == 255) carry_s = c + ex + v;
    __syncthreads();
  }
  if (threadIdx.x == 0) bbase[nb] = etot;
}

// ---- single-pass LDS-multisplit scatter with global atomic reservation ----
__global__ __launch_bounds__(256) void k_scatter1(
    const int* __restrict__ erow, const int* __restrict__ ecol,
    int* __restrict__ cursor, unsigned* __restrict__ sorted,
    int e, int chunk, int nb, int cap) {
  __shared__ unsigned staging[MS_CHUNK];  // 60KB
  __shared__ int lstart[256];
  __shared__ int lfill[256];
  __shared__ int gbase[256];
  __shared__ int wsum[4];
  int g = blockIdx.x;
  int s0 = g * chunk;
  int s1 = min(e, s0 + chunk);
  lfill[threadIdx.x] = 0;
  __syncthreads();
  // ---- pass A: local bucket counts ----
  {
    int i = s0 + threadIdx.x;
    for (; i + 768 < s1; i += 1024) {
      int c0 = ecol[i], c1 = ecol[i + 256], c2 = ecol[i + 512], c3 = ecol[i + 768];
      atomicAdd(&lfill[c0 >> 9], 1);
      atomicAdd(&lfill[c1 >> 9], 1);
      atomicAdd(&lfill[c2 >> 9], 1);
      atomicAdd(&lfill[c3 >> 9], 1);
    }
    for (; i < s1; i += 256) atomicAdd(&lfill[ecol[i] >> 9], 1);
  }
  __syncthreads();
  int cnt = lfill[threadIdx.x];
  int ex = blockScanExclusive256(cnt, wsum);
  lstart[threadIdx.x] = ex;
  int gb = 0;
  if (threadIdx.x < nb && cnt > 0) gb = atomicAdd(&cursor[threadIdx.x], cnt);
  gbase[threadIdx.x] = gb;
  __syncthreads();
  lfill[threadIdx.x] = 0;
  __syncthreads();
  // ---- pass B: scatter into LDS staging (ecol re-read is L2-hot) ----
  {
    int i = s0 + threadIdx.x;
    for (; i + 768 < s1; i += 1024) {
      int c0 = ecol[i],       c1 = ecol[i + 256], c2 = ecol[i + 512], c3 = ecol[i + 768];
      int r0 = erow[i],       r1 = erow[i + 256], r2 = erow[i + 512], r3 = erow[i + 768];
      int b0 = c0 >> 9, b1 = c1 >> 9, b2 = c2 >> 9, b3 = c3 >> 9;
      int p0 = atomicAdd(&lfill[b0], 1);
      int p1 = atomicAdd(&lfill[b1], 1);
      int p2 = atomicAdd(&lfill[b2], 1);
      int p3 = atomicAdd(&lfill[b3], 1);
      staging[lstart[b0] + p0] = ((unsigned)r0 << 9) | (unsigned)(c0 & 511);
      staging[lstart[b1] + p1] = ((unsigned)r1 << 9) | (unsigned)(c1 & 511);
      staging[lstart[b2] + p2] = ((unsigned)r2 << 9) | (unsigned)(c2 & 511);
      staging[lstart[b3] + p3] = ((unsigned)r3 << 9) | (unsigned)(c3 & 511);
    }
    for (; i < s1; i += 256) {
      int c = ecol[i];
      int b = c >> 9;
      int p = atomicAdd(&lfill[b], 1);
      staging[lstart[b] + p] = ((unsigned)erow[i] << 9) | (unsigned)(c & 511);
    }
  }
  __syncthreads();
  // ---- pass C: coalesced flush; wave w handles buckets w, w+4, ... ----
  int wid = threadIdx.x >> 6, L = threadIdx.x & 63;
  for (int b = wid; b < nb; b += 4) {
    int len = lfill[b];
    int ls = lstart[b];
    int gdst = b * cap + gbase[b];
    for (int j = L; j < len; j += 64)
      sorted[gdst + j] = staging[ls + j];
  }
}

// ---- layer-1 transform: wave per row, W1 (512x16) in regs, unscaled fp16.
//      Block 0 also zeroes the bucket cursors for k_scatter1. ----
__global__ __launch_bounds__(256) void k_transform1(
    const float* __restrict__ x, const float* __restrict__ W,
    __half* __restrict__ t1raw, int* __restrict__ cursor, int n) {
  if (blockIdx.x == 0) cursor[threadIdx.x] = 0;  // consumed by NEXT kernel

  int L = threadIdx.x & 63;
  int wid = blockIdx.x * 4 + (threadIdx.x >> 6);
  int nw = gridDim.x * 4;

  float w[8][16];
  const float4* W4 = reinterpret_cast<const float4*>(W);
#pragma unroll
  for (int i = 0; i < 4; ++i) {
#pragma unroll
    for (int c4 = 0; c4 < 4; ++c4) {
      float4 va = W4[(4 * L + i) * 4 + c4];
      w[i][c4 * 4 + 0] = va.x; w[i][c4 * 4 + 1] = va.y;
      w[i][c4 * 4 + 2] = va.z; w[i][c4 * 4 + 3] = va.w;
      float4 vb = W4[(256 + 4 * L + i) * 4 + c4];
      w[4 + i][c4 * 4 + 0] = vb.x; w[4 + i][c4 * 4 + 1] = vb.y;
      w[4 + i][c4 * 4 + 2] = vb.z; w[4 + i][c4 * 4 + 3] = vb.w;
    }
  }
  int col = ((L & 1) << 3) | ((L & 2) << 1) | ((L & 4) >> 1) | ((L & 8) >> 3);

  for (int r = wid; r < n; r += nw) {
    const float4* xr = reinterpret_cast<const float4*>(x + (size_t)r * 512);
    float4 v0 = xr[L];
    float4 v1 = xr[64 + L];
    float acc[16];
#pragma unroll
    for (int c = 0; c < 16; ++c) {
      float a = v0.x * w[0][c];
      a = fmaf(v0.y, w[1][c], a);
      a = fmaf(v0.z, w[2][c], a);
      a = fmaf(v0.w, w[3][c], a);
      a = fmaf(v1.x, w[4][c], a);
      a = fmaf(v1.y, w[5][c], a);
      a = fmaf(v1.z, w[6][c], a);
      a = fmaf(v1.w, w[7][c], a);
      acc[c] = a;
    }
#pragma unroll
    for (int j = 0; j < 8; ++j) {
      float send = (L & 1) ? acc[j] : acc[j + 8];
      float recv = __shfl_xor(send, 1, 64);
      acc[j] = ((L & 1) ? acc[j + 8] : acc[j]) + recv;
    }
#pragma unroll
    for (int j = 0; j < 4; ++j) {
      float send = (L & 2) ? acc[j] : acc[j + 4];
      float recv = __shfl_xor(send, 2, 64);
      acc[j] = ((L & 2) ? acc[j + 4] : acc[j]) + recv;
    }
#pragma unroll
    for (int j = 0; j < 2; ++j) {
      float send = (L & 4) ? acc[j] : acc[j + 2];
      float recv = __shfl_xor(send, 4, 64);
      acc[j] = ((L & 4) ? acc[j + 2] : acc[j]) + recv;
    }
    {
      float send = (L & 8) ? acc[0] : acc[1];
      float recv = __shfl_xor(send, 8, 64);
      acc[0] = ((L & 8) ? acc[1] : acc[0]) + recv;
    }
    float s = acc[0];
    s += __shfl_xor(s, 16, 64);
    s += __shfl_xor(s, 32, 64);
    if (L < 16) t1raw[r * 16 + col] = __float2half(s);
  }
}

// ---- pass2: per-bucket hist + scan + rowptr/dis + t1 scale + csr fill ----
__global__ __launch_bounds__(512) void k_pass2(const unsigned* __restrict__ sorted,
                                               const int* __restrict__ counts,
                                               const int* __restrict__ bbase,
                                               float* __restrict__ dis,
                                               int* __restrict__ rowptr,
                                               __half* __restrict__ t1,
                                               int* __restrict__ csr,
                                               int n, int etot, int cap) {
  __shared__ int hist[512];
  __shared__ int cur[512];
  __shared__ int wsum[8];
  int b = blockIdx.x;
  hist[threadIdx.x] = 0;
  __syncthreads();
  int s0 = b * cap;
  int s1 = s0 + counts[b];
  for (int i = s0 + threadIdx.x; i < s1; i += 512)
    atomicAdd(&hist[sorted[i] & 511], 1);
  __syncthreads();
  int j = threadIdx.x;
  int node = (b << 9) + j;
  int deg = hist[j];
  int ex = blockScanExclusive512(deg, wsum);
  float dv = rsqrtf((float)(deg + 1));  // +1 self loop
  int gpos = bbase[b] + ex;
  cur[j] = gpos;
  if (node < n) {
    dis[node] = dv;
    rowptr[node] = gpos;
    __half2* t2 = reinterpret_cast<__half2*>(t1 + ((size_t)node << 4));
#pragma unroll
    for (int q = 0; q < 8; ++q) {
      float2 fv = __half22float2(t2[q]);
      fv.x *= dv; fv.y *= dv;
      t2[q] = __float22half2_rn(fv);
    }
  }
  if (b == 0 && threadIdx.x == 0) rowptr[n] = etot;
  __syncthreads();
  for (int i = s0 + threadIdx.x; i < s1; i += 512) {
    unsigned v = sorted[i];
    int pos = atomicAdd(&cur[v & 511], 1);
    csr[pos] = (int)(v >> 9);
  }
}

// ---- wave-per-node gather: lane L = (edge-slot L>>4, feature L&15).
//      Per 16 edges: 1 coalesced csr load (16 words x4 replicas = 64B) +
//      4 ds_bpermute broadcasts + 4 hs VMEM instrs (4x32B segments each,
//      all for THIS node). Returns full neighbor+self sum in every lane
//      for feature f = L&15. ----
__device__ __forceinline__ float gather_wave(const __half* __restrict__ hs,
                                             const int* __restrict__ rowptr,
                                             const int* __restrict__ csr,
                                             int node, int L) {
  int f = L & 15;
  int es = L >> 4;  // edge slot 0..3
  int e0 = rowptr[node], e1 = rowptr[node + 1];
  float a0 = 0.f, a1 = 0.f, a2 = 0.f, a3 = 0.f;
  for (int e = e0; e < e1; e += 16) {
    int m = e + f;
    int rr = (m < e1) ? csr[m] : 0;  // lane f holds csr[e+f] (x4 replicas)
    int s0i = __shfl(rr, es, 64);
    int s1i = __shfl(rr, 4 + es, 64);
    int s2i = __shfl(rr, 8 + es, 64);
    int s3i = __shfl(rr, 12 + es, 64);
    if (e + es < e1)      a0 += __half2float(hs[(s0i << 4) + f]);
    if (e + 4 + es < e1)  a1 += __half2float(hs[(s1i << 4) + f]);
    if (e + 8 + es < e1)  a2 += __half2float(hs[(s2i << 4) + f]);
    if (e + 12 + es < e1) a3 += __half2float(hs[(s3i << 4) + f]);
  }
  float acc = (a0 + a1) + (a2 + a3);
  acc += __shfl_xor(acc, 16, 64);  // sum across edge slots
  acc += __shfl_xor(acc, 32, 64);
  acc += __half2float(hs[(node << 4) + f]);  // self loop (pre-scaled)
  return acc;
}

// out = relu(dis*acc + b) * dis   (layer-1 agg, prescaled for next gather)
__global__ __launch_bounds__(256) void k_agg_rb(
    const __half* __restrict__ hs, const int* __restrict__ rowptr,
    const int* __restrict__ csr, const float* __restrict__ dis,
    const float* __restrict__ b, __half* __restrict__ out, int n) {
  int L = threadIdx.x & 63;
  int node = blockIdx.x * 4 + (threadIdx.x >> 6);
  if (node >= n) return;
  float acc = gather_wave(hs, rowptr, csr, node, L);
  float d = dis[node];
  int f = L & 15;
  float t = fmaxf(fmaf(d, acc, b[f]), 0.f);
  if (L < 16) out[(node << 4) + f] = __float2half(t * d);
}

// mid: t3 = (relu((dis*acc)@W2 + b2) @ W3) * dis   -- 16->32->16 in-register
__global__ __launch_bounds__(256) void k_agg_mid(
    const __half* __restrict__ hs, const int* __restrict__ rowptr,
    const int* __restrict__ csr, const float* __restrict__ dis,
    const float* __restrict__ W2, const float* __restrict__ b2,
    const float* __restrict__ W3, __half* __restrict__ out, int n) {
  __shared__ float w2s[512];  // [16][32]
  __shared__ float w3s[512];  // [32][16]
  __shared__ float b2s[32];
  for (int i = threadIdx.x; i < 512; i += 256) { w2s[i] = W2[i]; w3s[i] = W3[i]; }
  if (threadIdx.x < 32) b2s[threadIdx.x] = b2[threadIdx.x];
  __syncthreads();
  int L = threadIdx.x & 63;
  int node = blockIdx.x * 4 + (threadIdx.x >> 6);
  if (node >= n) return;
  float acc = gather_wave(hs, rowptr, csr, node, L);
  float d = dis[node];
  float v = d * acc;  // g2[f], f = L&15, in every lane
  int f2 = L & 31;
  float a = b2s[f2];
#pragma unroll
  for (int k = 0; k < 16; ++k) {
    float vk = __shfl(v, k, 64);  // g2[k]
    a = fmaf(vk, w2s[k * 32 + f2], a);
  }
  a = fmaxf(a, 0.f);  // h2[f2] in lanes 0..31 (+replica 32..63)
  int f = L & 15;
  float t = 0.f;
#pragma unroll
  for (int c = 0; c < 32; ++c) {
    float hc = __shfl(a, c, 64);  // h2[c]
    t = fmaf(hc, w3s[c * 16 + f], t);
  }
  if (L < 16) out[(node << 4) + f] = __float2half(t * d);
}

// final: h = relu(dis*acc + b3) -> outh;  out = h@Wc + bc -> outc
__global__ __launch_bounds__(256) void k_agg_out(
    const __half* __restrict__ hs, const int* __restrict__ rowptr,
    const int* __restrict__ csr, const float* __restrict__ dis,
    const float* __restrict__ b3, const float* __restrict__ Wc,
    const float* __restrict__ bc, float* __restrict__ outh,
    float* __restrict__ outc, int n) {
  __shared__ float wcs[256];  // [16][16]
  __shared__ float b3s[16];
  __shared__ float bcs[16];
  if (threadIdx.x < 256) wcs[threadIdx.x] = Wc[threadIdx.x];
  if (threadIdx.x < 16) { b3s[threadIdx.x] = b3[threadIdx.x]; bcs[threadIdx.x] = bc[threadIdx.x]; }
  __syncthreads();
  int L = threadIdx.x & 63;
  int node = blockIdx.x * 4 + (threadIdx.x >> 6);
  if (node >= n) return;
  float acc = gather_wave(hs, rowptr, csr, node, L);
  float d = dis[node];
  int f = L & 15;
  float h = fmaxf(fmaf(d, acc, b3s[f]), 0.f);  // h[f] in every lane group
  if (L < 16) outh[(node << 4) + f] = h;
  float o = bcs[f];
#pragma unroll
  for (int k = 0; k < 16; ++k) {
    float hk = __shfl(h, k, 64);  // h[k]
    o = fmaf(hk, wcs[k * 16 + f], o);
  }
  if (L < 16) outc[(node << 4) + f] = o;
}

extern "C" void kernel_launch(void* const* d_in, const int* in_sizes, int n_in,
                              void* d_out, int out_size, void* d_ws, size_t ws_size,
                              hipStream_t stream) {
  (void)n_in; (void)out_size;
  const float* x  = (const float*)d_in[0];
  const int*   ei = (const int*)d_in[1];
  const float* W1 = (const float*)d_in[2];
  const float* b1 = (const float*)d_in[3];
  const float* W2 = (const float*)d_in[4];
  const float* b2 = (const float*)d_in[5];
  const float* W3 = (const float*)d_in[6];
  const float* b3 = (const float*)d_in[7];
  const float* Wc = (const float*)d_in[8];
  const float* bc = (const float*)d_in[9];

  const int F = 512;
  int N = in_sizes[0] / F;
  int E = in_sizes[1] / 2;
  const int* erow = ei;        // sources
  const int* ecol = ei + E;    // targets
  int NB = (N + 511) >> 9;     // buckets of 512 nodes (N<=131072)
  const int chunk = MS_CHUNK;  // 15360 edges per multisplit block
  int GS = (E + chunk - 1) / chunk;
  int CAP = ((E / NB) + 2048 + 511) & ~511;  // bucket capacity, ~mean+12sig

  auto align = [](size_t v) { return (v + 255) & ~(size_t)255; };
  char* p = (char*)d_ws;
  int*   cursor = (int*)p;   p += align(256 * 4);
  int*   bbase  = (int*)p;   p += align(257 * 4);
  float* dis    = (float*)p; p += align((size_t)N * 4);
  int*   rowptr = (int*)p;   p += align(((size_t)N + 1) * 4);
  int*   csr    = (int*)p;   p += align((size_t)E * 4);
  unsigned* sorted = (unsigned*)p; p += align((size_t)NB * CAP * 4);
  __half* bufA = (__half*)p; p += align((size_t)N * 16 * 2);
  __half* bufB = (__half*)p; p += align((size_t)N * 16 * 2);
  if ((size_t)(p - (char*)d_ws) > ws_size) return;  // fail visibly

  float* outc = (float*)d_out;                   // [N,16] classifier out
  float* outh = (float*)d_out + (size_t)N * 16;  // [N,16] h

  // ---- t1raw = x@W1 (unscaled fp16); block 0 zeroes bucket cursors ----
  k_transform1<<<2048, 256, 0, stream>>>(x, W1, bufA, cursor, N);
  // ---- single-pass multisplit scatter into fixed-capacity bucket regions ----
  k_scatter1<<<GS, 256, 0, stream>>>(erow, ecol, cursor, sorted, E, chunk, NB, CAP);
  // ---- bucket counts -> bbase ----
  k_bscan<<<1, 256, 0, stream>>>(cursor, bbase, NB, E);
  // ---- hist+scan+rowptr+dis, t1 *= dis, compact csr fill ----
  k_pass2<<<NB, 512, 0, stream>>>(sorted, cursor, bbase, dis, rowptr, bufA, csr, N, E, CAP);

  // ---- layers (wave-per-node aggs) ----
  int nblk = (N + 3) / 4;
  // hs1 = relu(dis*agg(t1)+b1)*dis  (fp16)
  k_agg_rb<<<nblk, 256, 0, stream>>>(bufA, rowptr, csr, dis, b1, bufB, N);
  // t3 = (relu((dis*agg(hs1))@W2+b2)@W3)*dis  (fp16)
  k_agg_mid<<<nblk, 256, 0, stream>>>(bufB, rowptr, csr, dis, W2, b2, W3, bufA, N);
  // h = relu(dis*agg(t3)+b3) -> outh;  out = h@Wc+bc -> outc  (fp32 outputs)
  k_agg_out<<<nblk, 256, 0, stream>>>(bufA, rowptr, csr, dis, b3, Wc, bc, outh, outc, N);
}

// Round 10
// 303.960 us; speedup vs baseline: 1.5688x; 1.5688x over previous
//
#include <hip/hip_runtime.h>
#include <hip/hip_bf16.h>
#include <hip/hip_fp16.h>
#include <stdint.h>

// ---------------------------------------------------------------------------
// GCN forward on MI355X.
//   CSR build via 196-bucket counting sort (bucket = col>>9, 512 nodes each).
//     k_transform1 : t1raw = x @ W1 (wave-per-row, W1 in regs, fp16 out,
//                    unscaled; dis applied in k_pass2). Block 0 also zeroes
//                    the 196 global bucket cursors.
//     k_scatter1   : single-pass LDS-multisplit scatter (count in LDS, scan,
//                    atomic-reserve per-bucket region, stage 60KB LDS
//                    bucket-ordered, coalesced flush). Rounds 3-6 lesson:
//                    scattered 4B stores over 25.6MB hit an L2 RMW wall;
//                    LDS-staged coalesced flush fixes it.
//     k_pass2      : per-bucket (512 thr): inline exclusive scan of bucket
//                    counts -> bbase[b] (k_bscan folded in, one fewer
//                    launch); LDS 512-hist of bucket region -> rowptr/dis,
//                    t1 *= dis, compact csr fill.
//   Layers (agg commutes with dense: A(XW)=(AX)W; 16->32->16 chain and the
//   classifier fused into agg epilogues; h2 never materialized):
//     t1  = (x @ W1) * dis                        (k_transform1 + k_pass2)
//     hs1 = relu(dis*gather(t1) + b1) * dis       (k_agg_rb)
//     t3  = (relu((dis*gather(hs1))@W2+b2)@W3)*dis (k_agg_mid)
//     h   = relu(dis*gather(t3) + b3) -> outh
//     out = h @ Wc + bc               -> outc      (k_agg_out)
//   AGG STRUCTURE (rounds 7-9 lesson, hard-won): group-per-node (16 lanes/
//   node, 4 nodes/wave) with DIRECT per-lane hs loads and 16-edge unroll is
//   the best measured form. The aggs are MLP/latency-bound: 16 independent
//   row loads in flight per wave is the winning property. Both "clever"
//   variants lost by putting shuffles on the critical path ahead of the
//   payload loads: shuffle-csr (+8us) and wave-per-node (130us/layer --
//   only ~4 loop iterations of a serial csr->shfl->load chain).
//   Gathered arrays (t1, hs1, t3) stored FP16 (3.2MB -> fits 4MB per-XCD
//   L2); fp32 accumulate. No fp atomics anywhere. 6 launches total.
// ---------------------------------------------------------------------------

#define MS_CHUNK 15360  // 60*256 edges per multisplit block (60KB staging)

__device__ __forceinline__ int blockScanExclusive256(int v, int* wsum) {
  int lane = threadIdx.x & 63;
  int wid  = threadIdx.x >> 6;
  int inc = v;
#pragma unroll
  for (int d = 1; d < 64; d <<= 1) {
    int y = __shfl_up(inc, d, 64);
    if (lane >= d) inc += y;
  }
  if (lane == 63) wsum[wid] = inc;
  __syncthreads();
  if (threadIdx.x == 0) {
    int s = 0;
#pragma unroll
    for (int w = 0; w < 4; ++w) { int t = wsum[w]; wsum[w] = s; s += t; }
  }
  __syncthreads();
  return inc - v + wsum[wid];
}

__device__ __forceinline__ int blockScanExclusive512(int v, int* wsum) {
  int lane = threadIdx.x & 63;
  int wid  = threadIdx.x >> 6;  // 0..7
  int inc = v;
#pragma unroll
  for (int d = 1; d < 64; d <<= 1) {
    int y = __shfl_up(inc, d, 64);
    if (lane >= d) inc += y;
  }
  if (lane == 63) wsum[wid] = inc;
  __syncthreads();
  if (threadIdx.x == 0) {
    int s = 0;
#pragma unroll
    for (int w = 0; w < 8; ++w) { int t = wsum[w]; wsum[w] = s; s += t; }
  }
  __syncthreads();
  return inc - v + wsum[wid];
}

// ---- single-pass LDS-multisplit scatter with global atomic reservation ----
__global__ __launch_bounds__(256) void k_scatter1(
    const int* __restrict__ erow, const int* __restrict__ ecol,
    int* __restrict__ cursor, unsigned* __restrict__ sorted,
    int e, int chunk, int nb, int cap) {
  __shared__ unsigned staging[MS_CHUNK];  // 60KB
  __shared__ int lstart[256];
  __shared__ int lfill[256];
  __shared__ int gbase[256];
  __shared__ int wsum[4];
  int g = blockIdx.x;
  int s0 = g * chunk;
  int s1 = min(e, s0 + chunk);
  lfill[threadIdx.x] = 0;
  __syncthreads();
  // ---- pass A: local bucket counts ----
  {
    int i = s0 + threadIdx.x;
    for (; i + 768 < s1; i += 1024) {
      int c0 = ecol[i], c1 = ecol[i + 256], c2 = ecol[i + 512], c3 = ecol[i + 768];
      atomicAdd(&lfill[c0 >> 9], 1);
      atomicAdd(&lfill[c1 >> 9], 1);
      atomicAdd(&lfill[c2 >> 9], 1);
      atomicAdd(&lfill[c3 >> 9], 1);
    }
    for (; i < s1; i += 256) atomicAdd(&lfill[ecol[i] >> 9], 1);
  }
  __syncthreads();
  int cnt = lfill[threadIdx.x];
  int ex = blockScanExclusive256(cnt, wsum);
  lstart[threadIdx.x] = ex;
  int gb = 0;
  if (threadIdx.x < nb && cnt > 0) gb = atomicAdd(&cursor[threadIdx.x], cnt);
  gbase[threadIdx.x] = gb;
  __syncthreads();
  lfill[threadIdx.x] = 0;
  __syncthreads();
  // ---- pass B: scatter into LDS staging (ecol re-read is L2-hot) ----
  {
    int i = s0 + threadIdx.x;
    for (; i + 768 < s1; i += 1024) {
      int c0 = ecol[i],       c1 = ecol[i + 256], c2 = ecol[i + 512], c3 = ecol[i + 768];
      int r0 = erow[i],       r1 = erow[i + 256], r2 = erow[i + 512], r3 = erow[i + 768];
      int b0 = c0 >> 9, b1 = c1 >> 9, b2 = c2 >> 9, b3 = c3 >> 9;
      int p0 = atomicAdd(&lfill[b0], 1);
      int p1 = atomicAdd(&lfill[b1], 1);
      int p2 = atomicAdd(&lfill[b2], 1);
      int p3 = atomicAdd(&lfill[b3], 1);
      staging[lstart[b0] + p0] = ((unsigned)r0 << 9) | (unsigned)(c0 & 511);
      staging[lstart[b1] + p1] = ((unsigned)r1 << 9) | (unsigned)(c1 & 511);
      staging[lstart[b2] + p2] = ((unsigned)r2 << 9) | (unsigned)(c2 & 511);
      staging[lstart[b3] + p3] = ((unsigned)r3 << 9) | (unsigned)(c3 & 511);
    }
    for (; i < s1; i += 256) {
      int c = ecol[i];
      int b = c >> 9;
      int p = atomicAdd(&lfill[b], 1);
      staging[lstart[b] + p] = ((unsigned)erow[i] << 9) | (unsigned)(c & 511);
    }
  }
  __syncthreads();
  // ---- pass C: coalesced flush; wave w handles buckets w, w+4, ... ----
  int wid = threadIdx.x >> 6, L = threadIdx.x & 63;
  for (int b = wid; b < nb; b += 4) {
    int len = lfill[b];
    int ls = lstart[b];
    int gdst = b * cap + gbase[b];
    for (int j = L; j < len; j += 64)
      sorted[gdst + j] = staging[ls + j];
  }
}

// ---- layer-1 transform: wave per row, W1 (512x16) in regs, unscaled fp16.
//      Block 0 also zeroes the bucket cursors for k_scatter1. ----
__global__ __launch_bounds__(256) void k_transform1(
    const float* __restrict__ x, const float* __restrict__ W,
    __half* __restrict__ t1raw, int* __restrict__ cursor, int n) {
  if (blockIdx.x == 0) cursor[threadIdx.x] = 0;  // consumed by NEXT kernel

  int L = threadIdx.x & 63;
  int wid = blockIdx.x * 4 + (threadIdx.x >> 6);
  int nw = gridDim.x * 4;

  float w[8][16];
  const float4* W4 = reinterpret_cast<const float4*>(W);
#pragma unroll
  for (int i = 0; i < 4; ++i) {
#pragma unroll
    for (int c4 = 0; c4 < 4; ++c4) {
      float4 va = W4[(4 * L + i) * 4 + c4];
      w[i][c4 * 4 + 0] = va.x; w[i][c4 * 4 + 1] = va.y;
      w[i][c4 * 4 + 2] = va.z; w[i][c4 * 4 + 3] = va.w;
      float4 vb = W4[(256 + 4 * L + i) * 4 + c4];
      w[4 + i][c4 * 4 + 0] = vb.x; w[4 + i][c4 * 4 + 1] = vb.y;
      w[4 + i][c4 * 4 + 2] = vb.z; w[4 + i][c4 * 4 + 3] = vb.w;
    }
  }
  int col = ((L & 1) << 3) | ((L & 2) << 1) | ((L & 4) >> 1) | ((L & 8) >> 3);

  for (int r = wid; r < n; r += nw) {
    const float4* xr = reinterpret_cast<const float4*>(x + (size_t)r * 512);
    float4 v0 = xr[L];
    float4 v1 = xr[64 + L];
    float acc[16];
#pragma unroll
    for (int c = 0; c < 16; ++c) {
      float a = v0.x * w[0][c];
      a = fmaf(v0.y, w[1][c], a);
      a = fmaf(v0.z, w[2][c], a);
      a = fmaf(v0.w, w[3][c], a);
      a = fmaf(v1.x, w[4][c], a);
      a = fmaf(v1.y, w[5][c], a);
      a = fmaf(v1.z, w[6][c], a);
      a = fmaf(v1.w, w[7][c], a);
      acc[c] = a;
    }
#pragma unroll
    for (int j = 0; j < 8; ++j) {
      float send = (L & 1) ? acc[j] : acc[j + 8];
      float recv = __shfl_xor(send, 1, 64);
      acc[j] = ((L & 1) ? acc[j + 8] : acc[j]) + recv;
    }
#pragma unroll
    for (int j = 0; j < 4; ++j) {
      float send = (L & 2) ? acc[j] : acc[j + 4];
      float recv = __shfl_xor(send, 2, 64);
      acc[j] = ((L & 2) ? acc[j + 4] : acc[j]) + recv;
    }
#pragma unroll
    for (int j = 0; j < 2; ++j) {
      float send = (L & 4) ? acc[j] : acc[j + 2];
      float recv = __shfl_xor(send, 4, 64);
      acc[j] = ((L & 4) ? acc[j + 2] : acc[j]) + recv;
    }
    {
      float send = (L & 8) ? acc[0] : acc[1];
      float recv = __shfl_xor(send, 8, 64);
      acc[0] = ((L & 8) ? acc[1] : acc[0]) + recv;
    }
    float s = acc[0];
    s += __shfl_xor(s, 16, 64);
    s += __shfl_xor(s, 32, 64);
    if (L < 16) t1raw[r * 16 + col] = __float2half(s);
  }
}

// ---- pass2: inline bbase scan + per-bucket hist + rowptr/dis + t1 scale +
//      csr fill ----
__global__ __launch_bounds__(512) void k_pass2(const unsigned* __restrict__ sorted,
                                               const int* __restrict__ counts,
                                               float* __restrict__ dis,
                                               int* __restrict__ rowptr,
                                               __half* __restrict__ t1,
                                               int* __restrict__ csr,
                                               int n, int etot, int cap, int nb) {
  __shared__ int hist[512];
  __shared__ int cur[512];
  __shared__ int wsum[8];
  __shared__ int cscan[512];
  int b = blockIdx.x;
  // inline exclusive scan of bucket counts -> bbase (k_bscan folded in)
  {
    int v = (threadIdx.x < nb) ? counts[threadIdx.x] : 0;
    int ex = blockScanExclusive512(v, wsum);
    cscan[threadIdx.x] = ex;
  }
  __syncthreads();
  int bbase_b = cscan[b];
  __syncthreads();
  hist[threadIdx.x] = 0;
  __syncthreads();
  int s0 = b * cap;
  int s1 = s0 + counts[b];
  for (int i = s0 + threadIdx.x; i < s1; i += 512)
    atomicAdd(&hist[sorted[i] & 511], 1);
  __syncthreads();
  int j = threadIdx.x;
  int node = (b << 9) + j;
  int deg = hist[j];
  int ex = blockScanExclusive512(deg, wsum);
  float dv = rsqrtf((float)(deg + 1));  // +1 self loop
  int gpos = bbase_b + ex;
  cur[j] = gpos;
  if (node < n) {
    dis[node] = dv;
    rowptr[node] = gpos;
    __half2* t2 = reinterpret_cast<__half2*>(t1 + ((size_t)node << 4));
#pragma unroll
    for (int q = 0; q < 8; ++q) {
      float2 fv = __half22float2(t2[q]);
      fv.x *= dv; fv.y *= dv;
      t2[q] = __float22half2_rn(fv);
    }
  }
  if (b == 0 && threadIdx.x == 0) rowptr[n] = etot;
  __syncthreads();
  for (int i = s0 + threadIdx.x; i < s1; i += 512) {
    unsigned v = sorted[i];
    int pos = atomicAdd(&cur[v & 511], 1);
    csr[pos] = (int)(v >> 9);
  }
}

// ---- common gather: acc = self + sum of neighbor rows (fp16 rows, fp32
//      accumulate). Group-per-node (16 lanes/node), DIRECT loads, 16-edge
//      unroll, 4 independent accumulators: 16 independent row loads in
//      flight per wave -- the MLP property that wins (rounds 7-9). ----
__device__ __forceinline__ float gather16(const __half* __restrict__ hs,
                                          const int* __restrict__ rowptr,
                                          const int* __restrict__ csr,
                                          int node, int f) {
  float acc0 = __half2float(hs[(node << 4) + f]);  // self loop (pre-scaled)
  int e0 = rowptr[node], e1 = rowptr[node + 1];
  int e = e0;
  float acc1 = 0.f, acc2 = 0.f, acc3 = 0.f;
  for (; e + 16 <= e1; e += 16) {
    int r0  = csr[e + 0],  r1  = csr[e + 1],  r2  = csr[e + 2],  r3  = csr[e + 3];
    int r4  = csr[e + 4],  r5  = csr[e + 5],  r6  = csr[e + 6],  r7  = csr[e + 7];
    int r8  = csr[e + 8],  r9  = csr[e + 9],  r10 = csr[e + 10], r11 = csr[e + 11];
    int r12 = csr[e + 12], r13 = csr[e + 13], r14 = csr[e + 14], r15 = csr[e + 15];
    __half v0  = hs[(r0  << 4) + f], v1  = hs[(r1  << 4) + f];
    __half v2  = hs[(r2  << 4) + f], v3  = hs[(r3  << 4) + f];
    __half v4  = hs[(r4  << 4) + f], v5  = hs[(r5  << 4) + f];
    __half v6  = hs[(r6  << 4) + f], v7  = hs[(r7  << 4) + f];
    __half v8  = hs[(r8  << 4) + f], v9  = hs[(r9  << 4) + f];
    __half v10 = hs[(r10 << 4) + f], v11 = hs[(r11 << 4) + f];
    __half v12 = hs[(r12 << 4) + f], v13 = hs[(r13 << 4) + f];
    __half v14 = hs[(r14 << 4) + f], v15 = hs[(r15 << 4) + f];
    acc0 += (__half2float(v0)  + __half2float(v1))  + (__half2float(v2)  + __half2float(v3));
    acc1 += (__half2float(v4)  + __half2float(v5))  + (__half2float(v6)  + __half2float(v7));
    acc2 += (__half2float(v8)  + __half2float(v9))  + (__half2float(v10) + __half2float(v11));
    acc3 += (__half2float(v12) + __half2float(v13)) + (__half2float(v14) + __half2float(v15));
  }
  for (; e + 4 <= e1; e += 4) {
    int r0 = csr[e + 0], r1 = csr[e + 1], r2 = csr[e + 2], r3 = csr[e + 3];
    float v0 = __half2float(hs[(r0 << 4) + f]), v1 = __half2float(hs[(r1 << 4) + f]);
    float v2 = __half2float(hs[(r2 << 4) + f]), v3 = __half2float(hs[(r3 << 4) + f]);
    acc0 += (v0 + v1) + (v2 + v3);
  }
  for (; e < e1; ++e) acc0 += __half2float(hs[(csr[e] << 4) + f]);
  return (acc0 + acc1) + (acc2 + acc3);
}

// out = relu(dis*acc + b) * dis   (layer-1 agg, prescaled for next gather)
__global__ __launch_bounds__(256) void k_agg_rb(
    const __half* __restrict__ hs, const int* __restrict__ rowptr,
    const int* __restrict__ csr, const float* __restrict__ dis,
    const float* __restrict__ b, __half* __restrict__ out, int n) {
  int node = blockIdx.x * 16 + threadIdx.x / 16;
  int f = threadIdx.x % 16;
  if (node >= n) return;
  float acc = gather16(hs, rowptr, csr, node, f);
  float d = dis[node];
  float t = fmaxf(fmaf(d, acc, b[f]), 0.f);
  out[(node << 4) + f] = __float2half(t * d);
}

// mid: t3 = (relu((dis*acc)@W2 + b2) @ W3) * dis   -- 16->32->16 in-register
__global__ __launch_bounds__(256) void k_agg_mid(
    const __half* __restrict__ hs, const int* __restrict__ rowptr,
    const int* __restrict__ csr, const float* __restrict__ dis,
    const float* __restrict__ W2, const float* __restrict__ b2,
    const float* __restrict__ W3, __half* __restrict__ out, int n) {
  __shared__ float w2s[512];  // [16][32]
  __shared__ float w3s[512];  // [32][16]
  __shared__ float b2s[32];
  for (int i = threadIdx.x; i < 512; i += 256) { w2s[i] = W2[i]; w3s[i] = W3[i]; }
  if (threadIdx.x < 32) b2s[threadIdx.x] = b2[threadIdx.x];
  __syncthreads();
  int node = blockIdx.x * 16 + threadIdx.x / 16;
  int f = threadIdx.x % 16;
  if (node >= n) return;
  float acc = gather16(hs, rowptr, csr, node, f);
  float d = dis[node];
  float v = d * acc;  // g2[f]
  int base = threadIdx.x & 48;  // 16-group base lane in wave
  float a0 = b2s[f], a1 = b2s[f + 16];
#pragma unroll
  for (int k = 0; k < 16; ++k) {
    float vk = __shfl(v, base + k, 64);
    a0 = fmaf(vk, w2s[k * 32 + f], a0);
    a1 = fmaf(vk, w2s[k * 32 + 16 + f], a1);
  }
  a0 = fmaxf(a0, 0.f);
  a1 = fmaxf(a1, 0.f);
  float t = 0.f;
#pragma unroll
  for (int c = 0; c < 16; ++c) {
    float h0 = __shfl(a0, base + c, 64);
    float h1 = __shfl(a1, base + c, 64);
    t = fmaf(h0, w3s[c * 16 + f], t);
    t = fmaf(h1, w3s[(c + 16) * 16 + f], t);
  }
  out[(node << 4) + f] = __float2half(t * d);
}

// final: h = relu(dis*acc + b3) -> outh;  out = h@Wc + bc -> outc
__global__ __launch_bounds__(256) void k_agg_out(
    const __half* __restrict__ hs, const int* __restrict__ rowptr,
    const int* __restrict__ csr, const float* __restrict__ dis,
    const float* __restrict__ b3, const float* __restrict__ Wc,
    const float* __restrict__ bc, float* __restrict__ outh,
    float* __restrict__ outc, int n) {
  __shared__ float wcs[256];  // [16][16]
  __shared__ float b3s[16];
  __shared__ float bcs[16];
  if (threadIdx.x < 256) wcs[threadIdx.x] = Wc[threadIdx.x];
  if (threadIdx.x < 16) { b3s[threadIdx.x] = b3[threadIdx.x]; bcs[threadIdx.x] = bc[threadIdx.x]; }
  __syncthreads();
  int node = blockIdx.x * 16 + threadIdx.x / 16;
  int f = threadIdx.x % 16;
  if (node >= n) return;
  float acc = gather16(hs, rowptr, csr, node, f);
  float d = dis[node];
  float h = fmaxf(fmaf(d, acc, b3s[f]), 0.f);
  outh[(node << 4) + f] = h;
  int base = threadIdx.x & 48;
  float o = bcs[f];
#pragma unroll
  for (int k = 0; k < 16; ++k) {
    float hk = __shfl(h, base + k, 64);
    o = fmaf(hk, wcs[k * 16 + f], o);
  }
  outc[(node << 4) + f] = o;
}

extern "C" void kernel_launch(void* const* d_in, const int* in_sizes, int n_in,
                              void* d_out, int out_size, void* d_ws, size_t ws_size,
                              hipStream_t stream) {
  (void)n_in; (void)out_size;
  const float* x  = (const float*)d_in[0];
  const int*   ei = (const int*)d_in[1];
  const float* W1 = (const float*)d_in[2];
  const float* b1 = (const float*)d_in[3];
  const float* W2 = (const float*)d_in[4];
  const float* b2 = (const float*)d_in[5];
  const float* W3 = (const float*)d_in[6];
  const float* b3 = (const float*)d_in[7];
  const float* Wc = (const float*)d_in[8];
  const float* bc = (const float*)d_in[9];

  const int F = 512;
  int N = in_sizes[0] / F;
  int E = in_sizes[1] / 2;
  const int* erow = ei;        // sources
  const int* ecol = ei + E;    // targets
  int NB = (N + 511) >> 9;     // buckets of 512 nodes (N<=131072)
  const int chunk = MS_CHUNK;  // 15360 edges per multisplit block
  int GS = (E + chunk - 1) / chunk;
  int CAP = ((E / NB) + 2048 + 511) & ~511;  // bucket capacity, ~mean+11sig

  auto align = [](size_t v) { return (v + 255) & ~(size_t)255; };
  char* p = (char*)d_ws;
  int*   cursor = (int*)p;   p += align(256 * 4);
  float* dis    = (float*)p; p += align((size_t)N * 4);
  int*   rowptr = (int*)p;   p += align(((size_t)N + 1) * 4);
  int*   csr    = (int*)p;   p += align((size_t)E * 4);
  unsigned* sorted = (unsigned*)p; p += align((size_t)NB * CAP * 4);
  __half* bufA = (__half*)p; p += align((size_t)N * 16 * 2);
  __half* bufB = (__half*)p; p += align((size_t)N * 16 * 2);
  if ((size_t)(p - (char*)d_ws) > ws_size) return;  // fail visibly

  float* outc = (float*)d_out;                   // [N,16] classifier out
  float* outh = (float*)d_out + (size_t)N * 16;  // [N,16] h

  // ---- t1raw = x@W1 (unscaled fp16); block 0 zeroes bucket cursors ----
  k_transform1<<<2048, 256, 0, stream>>>(x, W1, bufA, cursor, N);
  // ---- single-pass multisplit scatter into fixed-capacity bucket regions ----
  k_scatter1<<<GS, 256, 0, stream>>>(erow, ecol, cursor, sorted, E, chunk, NB, CAP);
  // ---- inline bbase scan + hist + rowptr/dis, t1 *= dis, compact csr ----
  k_pass2<<<NB, 512, 0, stream>>>(sorted, cursor, dis, rowptr, bufA, csr, N, E, CAP, NB);

  // ---- layers (group-per-node aggs, direct-load gather) ----
  // hs1 = relu(dis*agg(t1)+b1)*dis  (fp16)
  k_agg_rb<<<(N + 15) / 16, 256, 0, stream>>>(bufA, rowptr, csr, dis, b1, bufB, N);
  // t3 = (relu((dis*agg(hs1))@W2+b2)@W3)*dis  (fp16)
  k_agg_mid<<<(N + 15) / 16, 256, 0, stream>>>(bufB, rowptr, csr, dis, W2, b2, W3, bufA, N);
  // h = relu(dis*agg(t3)+b3) -> outh;  out = h@Wc+bc -> outc  (fp32 outputs)
  k_agg_out<<<(N + 15) / 16, 256, 0, stream>>>(bufA, rowptr, csr, dis, b3, Wc, bc, outh, outc, N);
}